// Round 1
// baseline (74.502 us; speedup 1.0000x reference)
//
#include <hip/hip_runtime.h>

#define BATCH 256
#define HWSZ  4096          // 64*64
#define COLS  16            // (h,w) columns per block
#define BSTR  17            // LDS row stride (+1 pad -> 2-way conflicts only, free)
#define CB    64            // core batch elements per block (4 chunks of 256)
#define XROWS (CB + 8)      // staged input rows: core + 2 halo rows per remaining layer

// One block = 16 (h,w) columns x one batch chunk of 64 (+halo), ALL 4 layers fused.
// The roll is along batch only, so columns are independent; batch is a circular
// 256-chain. Chunking the chain with halo recompute (+4.7% redundant VALU work)
// takes the grid from 256 blocks (1/CU, 1 wave/SIMD -- latency-bound) to 1024
// blocks (4/CU, 4 waves/SIMD -- latency hidden).
//   layer l computes cnt = 64 + 2*(3-l) rows: 70, 68, 66, 64.
// Regularizer stays exact: racc only accumulates core rows (idx < CB); halo rows
// are the neighbor chunk's core and are counted there.
__global__ __launch_bounds__(256, 4) void fused_kernel(
    const float* __restrict__ x,         // [256][4096]
    const float* __restrict__ tg,        // [4][16][4096]
    float* __restrict__ out,             // [256][4096]
    float* __restrict__ partials)        // [1024] per-block reg sums
{
    __shared__ float bufA[XROWS * BSTR];
    __shared__ float bufB[XROWS * BSTR];
    __shared__ float tws[64 * COLS];     // sigmoid(tg): 4 layers * 16 patterns
    __shared__ float wsum[4];

    const int tid = threadIdx.x;
    const int hw0 = blockIdx.x * COLS;
    const int b0  = blockIdx.y * CB;
    const int c   = tid & 15;
    const int r   = tid >> 4;            // 0..15

    // Stage sigmoid(tg): 4*16*16 = 1024 floats
#pragma unroll
    for (int k = 0; k < 4; ++k) {
        int idx = tid + k * 256;
        int c2 = idx & 15;
        int lp = idx >> 4;               // l*16 + p
        float g = tg[lp * HWSZ + hw0 + c2];
        tws[lp * COLS + c2] = 1.0f / (1.0f + __expf(-g));
    }

    // Stage x rows b0 .. b0+71 (mod 256) -> bufA (72 x 16 = 1152 floats)
#pragma unroll
    for (int k = 0; k < 5; ++k) {
        int idx = tid + k * 256;
        if (idx < XROWS * COLS) {
            int row = idx >> 4;
            int c2  = idx & 15;
            bufA[row * BSTR + c2] = x[((b0 + row) & 255) * HWSZ + hw0 + c2];
        }
    }

    float racc = 0.0f;
    float* src = bufA;
    float* dst = bufB;

#pragma unroll
    for (int l = 0; l < 4; ++l) {
        const int cnt = CB + 2 * (3 - l);   // 70, 68, 66, 64
        __syncthreads();

        // Per-layer sigmoid weights for this column; patterns 2/4, 3/5, 10/12,
        // 11/13 share identical w_p (j=1,j=2 both use v[b+1]) -> pre-sum.
        const float* tl = &tws[l * 16 * COLS + c];
        float T0  = tl[0 * COLS], T1 = tl[1 * COLS];
        float T24 = tl[2 * COLS] + tl[4 * COLS];
        float T35 = tl[3 * COLS] + tl[5 * COLS];
        float T6  = tl[6 * COLS], T7 = tl[7 * COLS];
        float T8  = tl[8 * COLS], T9 = tl[9 * COLS];
        float TAC = tl[10 * COLS] + tl[12 * COLS];
        float TBD = tl[11 * COLS] + tl[13 * COLS];
        float TE  = tl[14 * COLS], TF = tl[15 * COLS];

#pragma unroll
        for (int m = 0; m * 16 < CB + 2 * (3 - l); ++m) {
            int idx = r + 16 * m;
            if (idx < cnt) {
                float v0 = src[idx * BSTR + c];
                float v1 = src[(idx + 1) * BSTR + c];
                float v2 = src[(idx + 2) * BSTR + c];
                float a0 = 1.0f - v0, a1 = 1.0f - v1, a2 = 1.0f - v2;

                float g0 = a1 * a1, g1 = a1 * v1, g2 = v1 * v1;
                float u00 = a0 * g0, u01 = a0 * g1, u02 = a0 * g2;
                float u10 = v0 * g0, u11 = v0 * g1, u12 = v0 * g2;

                float w0 = u00 * a2, w1 = u00 * v2;
                float w2 = u01 * a2, w3 = u01 * v2;   // == patterns 4,5
                float w6 = u02 * a2, w7 = u02 * v2;
                float w8 = u10 * a2, w9 = u10 * v2;
                float wA = u11 * a2, wB = u11 * v2;   // == patterns 12,13
                float wE = u12 * a2, wF = u12 * v2;

                float acc = w0 * T0 + w1 * T1 + w2 * T24 + w3 * T35
                          + w6 * T6 + w7 * T7 + w8 * T8 + w9 * T9
                          + wA * TAC + wB * TBD + wE * TE + wF * TF;
                float o = fminf(fmaxf(acc, 0.0f), 1.0f);

                if (l == 3) out[(b0 + idx) * HWSZ + hw0 + c] = o;
                else        dst[idx * BSTR + c] = o;

                if (l >= 1 && idx < CB) {
                    // sum_p log(w_p)    = 8 * log(v0*a0 * (v1*a1)^2 * v2*a2)
                    // sum_p log(1-w_p)  = log( prod_p (1-w_p) ), dups squared
                    float s1 = (1.0f - w0) * (1.0f - w1) * (1.0f - w6) * (1.0f - w7)
                             * (1.0f - w8) * (1.0f - w9) * (1.0f - wE) * (1.0f - wF);
                    float s2 = (1.0f - w2) * (1.0f - w3) * (1.0f - wA) * (1.0f - wB);
                    float pB = s1 * s2 * s2;
                    float pA = (v0 * a0) * (g1 * g1) * (v2 * a2);
                    racc += 8.0f * __logf(pA) + __logf(pB);
                }
            }
        }
        float* t = src; src = dst; dst = t;
    }

    // Block reduction: wave shuffle (64) then cross-wave via LDS
#pragma unroll
    for (int off = 32; off; off >>= 1) racc += __shfl_down(racc, off, 64);
    if ((tid & 63) == 0) wsum[tid >> 6] = racc;
    __syncthreads();
    if (tid == 0)
        partials[blockIdx.y * gridDim.x + blockIdx.x] =
            wsum[0] + wsum[1] + wsum[2] + wsum[3];
}

__global__ void finalize_kernel(const float* __restrict__ partials,
                                float* __restrict__ out_reg)
{
    int tid = threadIdx.x;                 // 256 threads, 1024 partials
    double v = 0.0;
#pragma unroll
    for (int k = 0; k < 4; ++k) v += (double)partials[tid + k * 256];
#pragma unroll
    for (int off = 32; off; off >>= 1) v += __shfl_down(v, off, 64);
    __shared__ double ws[4];
    if ((tid & 63) == 0) ws[tid >> 6] = v;
    __syncthreads();
    if (tid == 0) {
        double tot = ws[0] + ws[1] + ws[2] + ws[3];
        // reg = -(sum of logs)/(256*64*64*16), output reg/3
        out_reg[0] = (float)(-tot / (16777216.0 * 3.0));
    }
}

extern "C" void kernel_launch(void* const* d_in, const int* in_sizes, int n_in,
                              void* d_out, int out_size, void* d_ws, size_t ws_size,
                              hipStream_t stream)
{
    const float* x  = (const float*)d_in[0];   // (256,64,64)
    const float* tg = (const float*)d_in[1];   // (4,16,64,64)
    float* out      = (float*)d_out;           // 1048576 outputs + 1 reg
    float* partials = (float*)d_ws;            // 1024 floats

    fused_kernel<<<dim3(HWSZ / COLS, BATCH / CB), dim3(256), 0, stream>>>(
        x, tg, out, partials);
    finalize_kernel<<<1, 256, 0, stream>>>(partials, out + (size_t)BATCH * HWSZ);
}